// Round 4
// baseline (234.706 us; speedup 1.0000x reference)
//
#include <hip/hip_runtime.h>

// out[b, 2n+o] = x[b,2n]*W[n,0,o] + x[b,2n+1]*W[n,1,o]
// W[n,m,o] = softmax_m(c[n,:,o]) = sigmoid(c[n,m,o] - c[n,1-m,o])
// Pure streaming: x read once (512 MiB), out written once (512 MiB).
// Grid-stride contiguous sweep; stride (524288 f32x4) is a multiple of the
// row length (2048 f32x4), so each thread's column chunk — and therefore its
// 2x2 weight set — is loop-invariant.
#define ELI_BATCH     16384
#define ELI_LAYER_IN  8192
#define ELI_NCHUNK    (ELI_LAYER_IN / 4)            // 2048 f32x4 per row
#define ELI_NTHREADS  (2048 * 256)                  // 524288 threads
#define ELI_TOTAL4    (ELI_BATCH * ELI_NCHUNK)      // 33554432 f32x4
#define ELI_ITERS     (ELI_TOTAL4 / ELI_NTHREADS)   // 64

typedef float f32x4 __attribute__((ext_vector_type(4)));

__global__ __launch_bounds__(256, 8)
void EfficientLearnableInterconnect_33913061769291_kernel(
        const float* __restrict__ x,
        const float* __restrict__ c,
        float* __restrict__ out) {
    const int tid   = blockIdx.x * 256 + threadIdx.x;   // 0..524287
    const int chunk = tid & (ELI_NCHUNK - 1);           // constant column chunk

    // c[n] as f32x4: (c[n,0,0], c[n,0,1], c[n,1,0], c[n,1,1])
    const f32x4 c0 = ((const f32x4*)c)[2 * chunk];
    const f32x4 c1 = ((const f32x4*)c)[2 * chunk + 1];

    const float w000 = 1.f / (1.f + __expf(c0.z - c0.x));
    const float w010 = 1.f / (1.f + __expf(c0.x - c0.z));
    const float w001 = 1.f / (1.f + __expf(c0.w - c0.y));
    const float w011 = 1.f / (1.f + __expf(c0.y - c0.w));
    const float w100 = 1.f / (1.f + __expf(c1.z - c1.x));
    const float w110 = 1.f / (1.f + __expf(c1.x - c1.z));
    const float w101 = 1.f / (1.f + __expf(c1.w - c1.y));
    const float w111 = 1.f / (1.f + __expf(c1.y - c1.w));

    const f32x4* __restrict__ xp = (const f32x4*)x + tid;
    f32x4* __restrict__       op = (f32x4*)out     + tid;

    #pragma unroll 8
    for (int r = 0; r < ELI_ITERS; ++r) {
        const f32x4 v = __builtin_nontemporal_load(xp + (size_t)r * ELI_NTHREADS);
        f32x4 o;
        o.x = v.x * w000 + v.y * w010;
        o.y = v.x * w001 + v.y * w011;
        o.z = v.z * w100 + v.w * w110;
        o.w = v.z * w101 + v.w * w111;
        __builtin_nontemporal_store(o, op + (size_t)r * ELI_NTHREADS);
    }
}

extern "C" void kernel_launch(void* const* d_in, const int* in_sizes, int n_in,
                              void* d_out, int out_size, void* d_ws, size_t ws_size,
                              hipStream_t stream) {
    const float* x = (const float*)d_in[0];
    const float* c = (const float*)d_in[1];
    float* out = (float*)d_out;

    const dim3 grid(ELI_NTHREADS / 256);  // 2048 blocks
    const dim3 block(256);
    EfficientLearnableInterconnect_33913061769291_kernel<<<grid, block, 0, stream>>>(x, c, out);
}